// Round 1
// baseline (2350.383 us; speedup 1.0000x reference)
//
#include <hip/hip_runtime.h>
#include <hip/hip_bf16.h>

// Problem constants (B=4, T=2048, C=1024, H=16, D=64)
constexpr int Bn = 4, Tn = 2048, Cn = 1024, Hn = 16, Dn = 64;
constexpr int Mn = Bn * Tn;        // 8192 rows
constexpr int QKV_N = 3 * Cn;      // 3072

__device__ __forceinline__ __hip_bfloat16 f2bf(float f) { return __float2bfloat16(f); }

// ---------------------------------------------------------------------------
// Kernel 1: QKV = x @ W_attn + b_attn, scattered to Q/K/V in [B,H,T,D] bf16.
// 64x64 tile, 256 threads, 4x4 microtile per thread, TK=16.
// ---------------------------------------------------------------------------
__global__ __launch_bounds__(256) void qkv_gemm_kernel(
    const float* __restrict__ x, const float* __restrict__ W,
    const float* __restrict__ bias,
    __hip_bfloat16* __restrict__ Q, __hip_bfloat16* __restrict__ K,
    __hip_bfloat16* __restrict__ V)
{
    __shared__ __align__(16) float As[16][68];  // [k][m] (A transposed)
    __shared__ __align__(16) float Bs[16][68];  // [k][n]
    const int tid = threadIdx.x;
    const int tx = tid & 15;        // n dir
    const int ty = tid >> 4;        // m dir
    const int m0 = blockIdx.x * 64;
    const int n0 = blockIdx.y * 64;

    const int arow = tid >> 2;           // 0..63
    const int akx  = (tid & 3) * 4;      // 0,4,8,12
    const int bk   = tid >> 4;           // 0..15
    const int bnx  = (tid & 15) * 4;     // 0..60

    float acc[4][4] = {};

    for (int k0 = 0; k0 < Cn; k0 += 16) {
        __syncthreads();
        float4 av = *(const float4*)(x + (size_t)(m0 + arow) * Cn + k0 + akx);
        As[akx + 0][arow] = av.x;
        As[akx + 1][arow] = av.y;
        As[akx + 2][arow] = av.z;
        As[akx + 3][arow] = av.w;
        float4 bv = *(const float4*)(W + (size_t)(k0 + bk) * QKV_N + n0 + bnx);
        *(float4*)&Bs[bk][bnx] = bv;
        __syncthreads();
#pragma unroll
        for (int k = 0; k < 16; ++k) {
            float4 a4 = *(const float4*)&As[k][ty * 4];
            float4 b4 = *(const float4*)&Bs[k][tx * 4];
            float aa[4] = {a4.x, a4.y, a4.z, a4.w};
            float bb[4] = {b4.x, b4.y, b4.z, b4.w};
#pragma unroll
            for (int i = 0; i < 4; ++i)
#pragma unroll
                for (int j = 0; j < 4; ++j) acc[i][j] += aa[i] * bb[j];
        }
    }

    // Epilogue: tile spans exactly one of Q/K/V and exactly one head.
    const int sel = n0 >> 10;             // 0=Q, 1=K, 2=V
    const int h   = (n0 & 1023) >> 6;     // head index
    __hip_bfloat16* O = (sel == 0) ? Q : ((sel == 1) ? K : V);
#pragma unroll
    for (int i = 0; i < 4; ++i) {
        int m = m0 + ty * 4 + i;
        int b = m >> 11;                  // / 2048
        int t = m & 2047;
        size_t rowbase = ((size_t)(b * Hn + h) * Tn + t) * Dn;
#pragma unroll
        for (int j = 0; j < 4; ++j) {
            int d = tx * 4 + j;
            float v = acc[i][j] + bias[n0 + d];
            O[rowbase + d] = f2bf(v);
        }
    }
}

// ---------------------------------------------------------------------------
// Kernel 2: causal flash attention, fp32 compute, bf16 in/out.
// Block = 256 threads handles 64 Q-rows of one (b,h). 4 threads per row
// (quad lanes), online softmax state replicated across the quad.
// ---------------------------------------------------------------------------
__global__ __launch_bounds__(256) void attn_kernel(
    const __hip_bfloat16* __restrict__ Q,
    const __hip_bfloat16* __restrict__ K,
    const __hip_bfloat16* __restrict__ V,
    __hip_bfloat16* __restrict__ Y)   // [B,T,C] bf16
{
    __shared__ __align__(16) float Ks[64][68];
    __shared__ __align__(16) float Vs[64][68];
    __shared__ __align__(16) float Ps[64][68];

    const int tid  = threadIdx.x;
    const int qt   = blockIdx.x;        // 0..31  (q tile)
    const int bh   = blockIdx.y;        // 0..63  (b*H + h)
    const int rloc = tid >> 2;          // 0..63
    const int g    = tid & 3;           // quad lane
    const int r_glob = qt * 64 + rloc;
    const size_t base = (size_t)bh * Tn * Dn;

    // q row in registers (fp32)
    float4 qreg[16];
    {
        const __hip_bfloat162* qp =
            (const __hip_bfloat162*)(Q + base + (size_t)r_glob * Dn);
#pragma unroll
        for (int i = 0; i < 16; ++i) {
            float2 a = __bfloat1622float2(qp[2 * i]);
            float2 b = __bfloat1622float2(qp[2 * i + 1]);
            qreg[i] = make_float4(a.x, a.y, b.x, b.y);
        }
    }

    float m_run = -1e30f, l_run = 0.f;
    float4 o4[4];
#pragma unroll
    for (int i = 0; i < 4; ++i) o4[i] = make_float4(0.f, 0.f, 0.f, 0.f);

    for (int kt = 0; kt <= qt; ++kt) {
        __syncthreads();   // previous tile's reads complete
        {
            const __hip_bfloat162* kp =
                (const __hip_bfloat162*)(K + base + (size_t)kt * 64 * Dn);
            const __hip_bfloat162* vp =
                (const __hip_bfloat162*)(V + base + (size_t)kt * 64 * Dn);
#pragma unroll
            for (int i = 0; i < 8; ++i) {
                int lin = tid + 256 * i;      // 0..2047
                int c  = lin >> 5;
                int d2 = lin & 31;
                float2 kf = __bfloat1622float2(kp[c * 32 + d2]);
                float2 vf = __bfloat1622float2(vp[c * 32 + d2]);
                *(float2*)&Ks[c][2 * d2] = kf;
                *(float2*)&Vs[c][2 * d2] = vf;
            }
        }
        __syncthreads();

        // scores for columns c = g + 4*jj
        float s[16];
#pragma unroll
        for (int jj = 0; jj < 16; ++jj) {
            int c = g + 4 * jj;
            float acc = 0.f;
#pragma unroll
            for (int d4 = 0; d4 < 16; ++d4) {
                float4 kv = *(const float4*)&Ks[c][d4 * 4];
                acc += qreg[d4].x * kv.x + qreg[d4].y * kv.y +
                       qreg[d4].z * kv.z + qreg[d4].w * kv.w;
            }
            acc *= 0.125f;  // 1/sqrt(64)
            if (kt == qt && (kt * 64 + c) > r_glob) acc = -1e30f;
            s[jj] = acc;
        }

        // online softmax (row state replicated across the quad)
        float mt = s[0];
#pragma unroll
        for (int jj = 1; jj < 16; ++jj) mt = fmaxf(mt, s[jj]);
        mt = fmaxf(mt, __shfl_xor(mt, 1));
        mt = fmaxf(mt, __shfl_xor(mt, 2));
        float m_new = fmaxf(m_run, mt);
        float alpha = __expf(m_run - m_new);
        float lsum = 0.f;
#pragma unroll
        for (int jj = 0; jj < 16; ++jj) {
            float p = __expf(s[jj] - m_new);
            s[jj] = p;
            lsum += p;
        }
        lsum += __shfl_xor(lsum, 1);
        lsum += __shfl_xor(lsum, 2);
        l_run = l_run * alpha + lsum;
        m_run = m_new;
#pragma unroll
        for (int i = 0; i < 4; ++i) {
            o4[i].x *= alpha; o4[i].y *= alpha;
            o4[i].z *= alpha; o4[i].w *= alpha;
        }

#pragma unroll
        for (int jj = 0; jj < 16; ++jj) Ps[rloc][g + 4 * jj] = s[jj];
        __syncthreads();

        // PV: this thread accumulates dims g*16 .. g*16+15
#pragma unroll 8
        for (int c = 0; c < 64; ++c) {
            float p = Ps[rloc][c];
#pragma unroll
            for (int d4 = 0; d4 < 4; ++d4) {
                float4 vv = *(const float4*)&Vs[c][g * 16 + d4 * 4];
                o4[d4].x += p * vv.x;
                o4[d4].y += p * vv.y;
                o4[d4].z += p * vv.z;
                o4[d4].w += p * vv.w;
            }
        }
    }

    // epilogue: Y[b, t, h*64 + d]
    float inv_l = 1.f / l_run;
    int b = bh >> 4;
    int h = bh & 15;
    size_t yb = ((size_t)b * Tn + r_glob) * Cn + h * Dn + g * 16;
#pragma unroll
    for (int d4 = 0; d4 < 4; ++d4) {
        Y[yb + d4 * 4 + 0] = f2bf(o4[d4].x * inv_l);
        Y[yb + d4 * 4 + 1] = f2bf(o4[d4].y * inv_l);
        Y[yb + d4 * 4 + 2] = f2bf(o4[d4].z * inv_l);
        Y[yb + d4 * 4 + 3] = f2bf(o4[d4].w * inv_l);
    }
}

// ---------------------------------------------------------------------------
// Kernel 3: out = Y @ W_proj + b_proj  (Y bf16, out fp32). Same tiling as K1.
// ---------------------------------------------------------------------------
__global__ __launch_bounds__(256) void proj_gemm_kernel(
    const __hip_bfloat16* __restrict__ Yb, const float* __restrict__ W,
    const float* __restrict__ bias, float* __restrict__ out)
{
    __shared__ __align__(16) float As[16][68];
    __shared__ __align__(16) float Bs[16][68];
    const int tid = threadIdx.x;
    const int tx = tid & 15;
    const int ty = tid >> 4;
    const int m0 = blockIdx.x * 64;
    const int n0 = blockIdx.y * 64;

    const int arow = tid >> 2;
    const int akx  = (tid & 3) * 4;
    const int bk   = tid >> 4;
    const int bnx  = (tid & 15) * 4;

    float acc[4][4] = {};

    for (int k0 = 0; k0 < Cn; k0 += 16) {
        __syncthreads();
        {
            const __hip_bfloat162* ap =
                (const __hip_bfloat162*)(Yb + (size_t)(m0 + arow) * Cn + k0 + akx);
            float2 a0 = __bfloat1622float2(ap[0]);
            float2 a1 = __bfloat1622float2(ap[1]);
            As[akx + 0][arow] = a0.x;
            As[akx + 1][arow] = a0.y;
            As[akx + 2][arow] = a1.x;
            As[akx + 3][arow] = a1.y;
        }
        float4 bv = *(const float4*)(W + (size_t)(k0 + bk) * Cn + n0 + bnx);
        *(float4*)&Bs[bk][bnx] = bv;
        __syncthreads();
#pragma unroll
        for (int k = 0; k < 16; ++k) {
            float4 a4 = *(const float4*)&As[k][ty * 4];
            float4 b4 = *(const float4*)&Bs[k][tx * 4];
            float aa[4] = {a4.x, a4.y, a4.z, a4.w};
            float bb[4] = {b4.x, b4.y, b4.z, b4.w};
#pragma unroll
            for (int i = 0; i < 4; ++i)
#pragma unroll
                for (int j = 0; j < 4; ++j) acc[i][j] += aa[i] * bb[j];
        }
    }

#pragma unroll
    for (int i = 0; i < 4; ++i) {
        int m = m0 + ty * 4 + i;
#pragma unroll
        for (int j = 0; j < 4; ++j) {
            int n = n0 + tx * 4 + j;
            out[(size_t)m * Cn + n] = acc[i][j] + bias[n];
        }
    }
}

// ---------------------------------------------------------------------------
extern "C" void kernel_launch(void* const* d_in, const int* in_sizes, int n_in,
                              void* d_out, int out_size, void* d_ws, size_t ws_size,
                              hipStream_t stream) {
    const float* x      = (const float*)d_in[0];
    const float* W_attn = (const float*)d_in[1];
    const float* b_attn = (const float*)d_in[2];
    const float* W_proj = (const float*)d_in[3];
    const float* b_proj = (const float*)d_in[4];
    float* out = (float*)d_out;

    // Workspace layout (bf16): Q, K, V in [B,H,T,D], Y in [B,T,C]
    constexpr size_t PER = (size_t)Mn * Cn;  // 8388608 elems each
    __hip_bfloat16* Qb = (__hip_bfloat16*)d_ws;
    __hip_bfloat16* Kb = Qb + PER;
    __hip_bfloat16* Vb = Kb + PER;
    __hip_bfloat16* Yb = Vb + PER;

    qkv_gemm_kernel<<<dim3(Mn / 64, QKV_N / 64), 256, 0, stream>>>(
        x, W_attn, b_attn, Qb, Kb, Vb);
    attn_kernel<<<dim3(Tn / 64, Bn * Hn), 256, 0, stream>>>(Qb, Kb, Vb, Yb);
    proj_gemm_kernel<<<dim3(Mn / 64, Cn / 64), 256, 0, stream>>>(
        Yb, W_proj, b_proj, out);
}

// Round 3
// 429.970 us; speedup vs baseline: 5.4664x; 5.4664x over previous
//
#include <hip/hip_runtime.h>
#include <hip/hip_bf16.h>

typedef short s16x8 __attribute__((ext_vector_type(8)));
typedef float f32x4 __attribute__((ext_vector_type(4)));

#define MFMA_BF16(A, B, C) __builtin_amdgcn_mfma_f32_16x16x32_bf16(A, B, C, 0, 0, 0)

constexpr int Bn = 4, Tn = 2048, Cn = 1024, Hn = 16, Dn = 64;
constexpr int Mn = Bn * Tn;      // 8192
constexpr int Nqkv = 3 * Cn;     // 3072

__device__ __forceinline__ ushort f2bfu(float f) {
    __hip_bfloat16 h = __float2bfloat16(f);
    return *reinterpret_cast<ushort*>(&h);
}

// ---------------------------------------------------------------------------
// fp32 -> bf16 elementwise (x)
// ---------------------------------------------------------------------------
__global__ __launch_bounds__(256) void conv_bf16_kernel(
    const float* __restrict__ src, ushort* __restrict__ dst, int n4)
{
    int i = blockIdx.x * blockDim.x + threadIdx.x;
    int stride = gridDim.x * blockDim.x;
    for (; i < n4; i += stride) {
        float4 v = ((const float4*)src)[i];
        ushort4 o;
        o.x = f2bfu(v.x); o.y = f2bfu(v.y); o.z = f2bfu(v.z); o.w = f2bfu(v.w);
        ((ushort4*)dst)[i] = o;
    }
}

// ---------------------------------------------------------------------------
// W [K][N] fp32  ->  Wt [N][K] bf16   (64x64 tiles via LDS)
// ---------------------------------------------------------------------------
__global__ __launch_bounds__(256) void transpose_cvt_kernel(
    const float* __restrict__ W, ushort* __restrict__ Wt, int K, int N)
{
    __shared__ __align__(16) float Ls[64][68];
    const int t = threadIdx.x;
    const int n0 = blockIdx.x * 64, k0 = blockIdx.y * 64;
#pragma unroll
    for (int p = 0; p < 4; ++p) {
        int r = (t >> 4) + p * 16;
        int c = (t & 15) * 4;
        *(float4*)&Ls[r][c] = *(const float4*)&W[(size_t)(k0 + r) * N + n0 + c];
    }
    __syncthreads();
    const int n = t >> 2;
    const int ks = (t & 3) * 16;
    union { ushort s[16]; uint4 u[2]; } tmp;
#pragma unroll
    for (int j = 0; j < 16; ++j) tmp.s[j] = f2bfu(Ls[ks + j][n]);
    uint4* dp = (uint4*)&Wt[(size_t)(n0 + n) * K + k0 + ks];
    dp[0] = tmp.u[0];
    dp[1] = tmp.u[1];
}

// ---------------------------------------------------------------------------
// QKV GEMM: A [8192][1024] bf16, Bt [3072][1024] bf16 -> Q/K/V [B,H,T,D] bf16
// 128x128 tile, BK=64, 4 waves, each wave 64x64 (4x4 MFMA 16x16x32 accs)
// ---------------------------------------------------------------------------
__global__ __launch_bounds__(256) void qkv_gemm_mfma(
    const ushort* __restrict__ A, const ushort* __restrict__ Bt,
    const float* __restrict__ bias,
    ushort* __restrict__ Qo, ushort* __restrict__ Ko, ushort* __restrict__ Vo)
{
    __shared__ __align__(16) ushort As[128][72];
    __shared__ __align__(16) ushort Bs[128][72];
    const int tid = threadIdx.x;
    const int m0 = blockIdx.x * 128, n0 = blockIdx.y * 128;
    const int w = tid >> 6, lane = tid & 63, l15 = lane & 15, qd = lane >> 4;
    const int wm = (w >> 1) * 64, wn = (w & 1) * 64;
    const int srow = tid >> 1, sseg = (tid & 1) * 32;

    f32x4 acc[4][4] = {};

    const uint4* ga = (const uint4*)(A + (size_t)(m0 + srow) * Cn + sseg);
    const uint4* gb = (const uint4*)(Bt + (size_t)(n0 + srow) * Cn + sseg);

    for (int k0 = 0; k0 < Cn; k0 += 64) {
        __syncthreads();
        uint4 a0 = ga[0], a1 = ga[1], a2 = ga[2], a3 = ga[3];
        uint4 b0 = gb[0], b1 = gb[1], b2 = gb[2], b3 = gb[3];
        ga += 8; gb += 8;
        *(uint4*)&As[srow][sseg +  0] = a0;
        *(uint4*)&As[srow][sseg +  8] = a1;
        *(uint4*)&As[srow][sseg + 16] = a2;
        *(uint4*)&As[srow][sseg + 24] = a3;
        *(uint4*)&Bs[srow][sseg +  0] = b0;
        *(uint4*)&Bs[srow][sseg +  8] = b1;
        *(uint4*)&Bs[srow][sseg + 16] = b2;
        *(uint4*)&Bs[srow][sseg + 24] = b3;
        __syncthreads();
#pragma unroll
        for (int ks = 0; ks < 2; ++ks) {
            s16x8 af[4], bfr[4];
#pragma unroll
            for (int i = 0; i < 4; ++i) {
                af[i]  = *(const s16x8*)&As[wm + i * 16 + l15][ks * 32 + qd * 8];
                bfr[i] = *(const s16x8*)&Bs[wn + i * 16 + l15][ks * 32 + qd * 8];
            }
#pragma unroll
            for (int mt = 0; mt < 4; ++mt)
#pragma unroll
                for (int nt = 0; nt < 4; ++nt)
                    acc[mt][nt] = MFMA_BF16(af[mt], bfr[nt], acc[mt][nt]);
        }
    }

#pragma unroll
    for (int nt = 0; nt < 4; ++nt) {
        int n_g = n0 + wn + nt * 16 + l15;
        float bv = bias[n_g];
        int sel = n_g >> 10;
        int h = (n_g >> 6) & 15;
        int d = n_g & 63;
        ushort* O = (sel == 0) ? Qo : ((sel == 1) ? Ko : Vo);
#pragma unroll
        for (int mt = 0; mt < 4; ++mt) {
#pragma unroll
            for (int r = 0; r < 4; ++r) {
                int m_g = m0 + wm + mt * 16 + qd * 4 + r;
                int b = m_g >> 11, t = m_g & 2047;
                O[(((size_t)(b * Hn + h) * Tn + t) << 6) + d] =
                    f2bfu(acc[mt][nt][r] + bv);
            }
        }
    }
}

// ---------------------------------------------------------------------------
// MFMA flash attention. Block = 256 thr = 4 waves; 64 Q-rows of one (b,h).
// Wave w owns Q rows w*16..w*16+16. QK^T and PV on matrix cores.
// Staging: 64x64 bf16 tile = 4096 ushorts; 256 threads x 16 ushorts
// (srow = tid>>2 in [0,64), sseg = (tid&3)*16).
// ---------------------------------------------------------------------------
__global__ __launch_bounds__(256) void attn_mfma(
    const ushort* __restrict__ Q, const ushort* __restrict__ K,
    const ushort* __restrict__ V, ushort* __restrict__ Y)
{
    __shared__ __align__(16) ushort QPs[64][72];  // Q tile, then per-wave P
    __shared__ __align__(16) ushort Ks[64][72];   // [key][d]
    __shared__ __align__(16) ushort Vt[64][72];   // [d][key]

    const int tid = threadIdx.x;
    const int qt = blockIdx.x, bh = blockIdx.y;
    const int w = tid >> 6, lane = tid & 63, l15 = lane & 15, qd = lane >> 4;
    const size_t base = (size_t)bh * Tn * Dn;
    const int srow = tid >> 2;          // 0..63
    const int sseg = (tid & 3) * 16;    // 0,16,32,48

    // stage Q tile (64 rows x 64 cols bf16)
    {
        const uint4* gq = (const uint4*)(Q + base + (size_t)(qt * 64 + srow) * Dn + sseg);
        uint4 q0 = gq[0], q1 = gq[1];
        *(uint4*)&QPs[srow][sseg + 0] = q0;
        *(uint4*)&QPs[srow][sseg + 8] = q1;
    }
    __syncthreads();
    s16x8 qf[2];
    qf[0] = *(const s16x8*)&QPs[w * 16 + l15][qd * 8];
    qf[1] = *(const s16x8*)&QPs[w * 16 + l15][32 + qd * 8];

    float m_run[4] = {-1e30f, -1e30f, -1e30f, -1e30f};
    float l_run[4] = {0.f, 0.f, 0.f, 0.f};
    f32x4 o[4] = {};

    for (int kt = 0; kt <= qt; ++kt) {
        __syncthreads();   // protect Ks/Vt reads of previous iteration
        {
            const uint4* gk = (const uint4*)(K + base + (size_t)(kt * 64 + srow) * Dn + sseg);
            uint4 k0 = gk[0], k1 = gk[1];
            *(uint4*)&Ks[srow][sseg + 0] = k0;
            *(uint4*)&Ks[srow][sseg + 8] = k1;
            int vkey = tid & 63, vds = (tid >> 6) * 16;
            const uint4* gv = (const uint4*)(V + base + (size_t)(kt * 64 + vkey) * Dn + vds);
            union { uint4 u[2]; ushort s[16]; } vb;
            vb.u[0] = gv[0]; vb.u[1] = gv[1];
#pragma unroll
            for (int j = 0; j < 16; ++j) Vt[vds + j][vkey] = vb.s[j];
        }
        __syncthreads();

        // S = Q K^T (scaled)
        f32x4 s[4] = {};
#pragma unroll
        for (int ks = 0; ks < 2; ++ks) {
            s16x8 kf[4];
#pragma unroll
            for (int nt = 0; nt < 4; ++nt)
                kf[nt] = *(const s16x8*)&Ks[nt * 16 + l15][ks * 32 + qd * 8];
#pragma unroll
            for (int nt = 0; nt < 4; ++nt)
                s[nt] = MFMA_BF16(qf[ks], kf[nt], s[nt]);
        }
#pragma unroll
        for (int nt = 0; nt < 4; ++nt)
#pragma unroll
            for (int r = 0; r < 4; ++r) s[nt][r] *= 0.125f;

        if (kt == qt) {
            // causal mask within the diagonal tile (local indices)
#pragma unroll
            for (int nt = 0; nt < 4; ++nt) {
                int k_l = nt * 16 + l15;
#pragma unroll
                for (int r = 0; r < 4; ++r) {
                    int q_l = w * 16 + qd * 4 + r;
                    if (k_l > q_l) s[nt][r] = -1e30f;
                }
            }
        }

        // online softmax, per output row r (row = qd*4+r, state replicated
        // across the 16 lanes of the quad group)
#pragma unroll
        for (int r = 0; r < 4; ++r) {
            float mr = fmaxf(fmaxf(s[0][r], s[1][r]), fmaxf(s[2][r], s[3][r]));
            mr = fmaxf(mr, __shfl_xor(mr, 1));
            mr = fmaxf(mr, __shfl_xor(mr, 2));
            mr = fmaxf(mr, __shfl_xor(mr, 4));
            mr = fmaxf(mr, __shfl_xor(mr, 8));
            float mnew = fmaxf(m_run[r], mr);
            float alpha = __expf(m_run[r] - mnew);
            m_run[r] = mnew;
            float ls = 0.f;
#pragma unroll
            for (int nt = 0; nt < 4; ++nt) {
                float p = __expf(s[nt][r] - mnew);
                s[nt][r] = p;
                ls += p;
            }
            ls += __shfl_xor(ls, 1);
            ls += __shfl_xor(ls, 2);
            ls += __shfl_xor(ls, 4);
            ls += __shfl_xor(ls, 8);
            l_run[r] = l_run[r] * alpha + ls;
#pragma unroll
            for (int dt = 0; dt < 4; ++dt) o[dt][r] *= alpha;
        }

        // P (C-layout) -> LDS (wave-private rows) -> A-layout fragments
#pragma unroll
        for (int nt = 0; nt < 4; ++nt)
#pragma unroll
            for (int r = 0; r < 4; ++r)
                QPs[w * 16 + qd * 4 + r][nt * 16 + l15] = f2bfu(s[nt][r]);

#pragma unroll
        for (int ks = 0; ks < 2; ++ks) {
            s16x8 pa = *(const s16x8*)&QPs[w * 16 + l15][ks * 32 + qd * 8];
#pragma unroll
            for (int nt = 0; nt < 4; ++nt) {
                s16x8 vf = *(const s16x8*)&Vt[nt * 16 + l15][ks * 32 + qd * 8];
                o[nt] = MFMA_BF16(pa, vf, o[nt]);
            }
        }
    }

    // epilogue: Y[b, t, h*64 + d]
    const int b = bh >> 4, h = bh & 15;
#pragma unroll
    for (int r = 0; r < 4; ++r) {
        float inv = 1.f / l_run[r];
        int t_g = qt * 64 + w * 16 + qd * 4 + r;
        size_t yb = ((size_t)(b * Tn + t_g)) * Cn + h * Dn;
#pragma unroll
        for (int nt = 0; nt < 4; ++nt)
            Y[yb + nt * 16 + l15] = f2bfu(o[nt][r] * inv);
    }
}

// ---------------------------------------------------------------------------
// Proj GEMM: Y [8192][1024] bf16, Wt [1024][1024] bf16 -> out fp32
// ---------------------------------------------------------------------------
__global__ __launch_bounds__(256) void proj_gemm_mfma(
    const ushort* __restrict__ A, const ushort* __restrict__ Bt,
    const float* __restrict__ bias, float* __restrict__ out)
{
    __shared__ __align__(16) ushort As[128][72];
    __shared__ __align__(16) ushort Bs[128][72];
    const int tid = threadIdx.x;
    const int m0 = blockIdx.x * 128, n0 = blockIdx.y * 128;
    const int w = tid >> 6, lane = tid & 63, l15 = lane & 15, qd = lane >> 4;
    const int wm = (w >> 1) * 64, wn = (w & 1) * 64;
    const int srow = tid >> 1, sseg = (tid & 1) * 32;

    f32x4 acc[4][4] = {};

    const uint4* ga = (const uint4*)(A + (size_t)(m0 + srow) * Cn + sseg);
    const uint4* gb = (const uint4*)(Bt + (size_t)(n0 + srow) * Cn + sseg);

    for (int k0 = 0; k0 < Cn; k0 += 64) {
        __syncthreads();
        uint4 a0 = ga[0], a1 = ga[1], a2 = ga[2], a3 = ga[3];
        uint4 b0 = gb[0], b1 = gb[1], b2 = gb[2], b3 = gb[3];
        ga += 8; gb += 8;
        *(uint4*)&As[srow][sseg +  0] = a0;
        *(uint4*)&As[srow][sseg +  8] = a1;
        *(uint4*)&As[srow][sseg + 16] = a2;
        *(uint4*)&As[srow][sseg + 24] = a3;
        *(uint4*)&Bs[srow][sseg +  0] = b0;
        *(uint4*)&Bs[srow][sseg +  8] = b1;
        *(uint4*)&Bs[srow][sseg + 16] = b2;
        *(uint4*)&Bs[srow][sseg + 24] = b3;
        __syncthreads();
#pragma unroll
        for (int ks = 0; ks < 2; ++ks) {
            s16x8 af[4], bfr[4];
#pragma unroll
            for (int i = 0; i < 4; ++i) {
                af[i]  = *(const s16x8*)&As[wm + i * 16 + l15][ks * 32 + qd * 8];
                bfr[i] = *(const s16x8*)&Bs[wn + i * 16 + l15][ks * 32 + qd * 8];
            }
#pragma unroll
            for (int mt = 0; mt < 4; ++mt)
#pragma unroll
                for (int nt = 0; nt < 4; ++nt)
                    acc[mt][nt] = MFMA_BF16(af[mt], bfr[nt], acc[mt][nt]);
        }
    }

#pragma unroll
    for (int nt = 0; nt < 4; ++nt) {
        int n_g = n0 + wn + nt * 16 + l15;
        float bv = bias[n_g];
#pragma unroll
        for (int mt = 0; mt < 4; ++mt) {
#pragma unroll
            for (int r = 0; r < 4; ++r) {
                int m_g = m0 + wm + mt * 16 + qd * 4 + r;
                out[(size_t)m_g * Cn + n_g] = acc[mt][nt][r] + bv;
            }
        }
    }
}

// ---------------------------------------------------------------------------
extern "C" void kernel_launch(void* const* d_in, const int* in_sizes, int n_in,
                              void* d_out, int out_size, void* d_ws, size_t ws_size,
                              hipStream_t stream) {
    const float* x      = (const float*)d_in[0];
    const float* W_attn = (const float*)d_in[1];
    const float* b_attn = (const float*)d_in[2];
    const float* W_proj = (const float*)d_in[3];
    const float* b_proj = (const float*)d_in[4];
    float* out = (float*)d_out;

    // ws: Q, K, V [B,H,T,D] bf16, Y [B,T,C] bf16
    constexpr size_t PER = (size_t)Mn * Cn;  // 8388608 elems
    ushort* Qb = (ushort*)d_ws;
    ushort* Kb = Qb + PER;
    ushort* Vb = Kb + PER;
    ushort* Yb = Vb + PER;

    // d_out doubles as pre-pass scratch (23 MB < 33.5 MB), dead before proj:
    //   WtA = W_attn^T bf16 [3072][1024], x_bf = x bf16 [8192][1024]
    ushort* WtA  = (ushort*)d_out;
    ushort* x_bf = WtA + (size_t)Nqkv * Cn;
    // Wt_proj reuses Q's buffer (Q dead after attention)
    ushort* WtP  = Qb;

    conv_bf16_kernel<<<1024, 256, 0, stream>>>(x, x_bf, (int)(PER / 4));
    transpose_cvt_kernel<<<dim3(Nqkv / 64, Cn / 64), 256, 0, stream>>>(
        W_attn, WtA, Cn, Nqkv);
    qkv_gemm_mfma<<<dim3(Mn / 128, Nqkv / 128), 256, 0, stream>>>(
        x_bf, WtA, b_attn, Qb, Kb, Vb);
    attn_mfma<<<dim3(Tn / 64, Bn * Hn), 256, 0, stream>>>(Qb, Kb, Vb, Yb);
    transpose_cvt_kernel<<<dim3(Cn / 64, Cn / 64), 256, 0, stream>>>(
        W_proj, WtP, Cn, Cn);
    proj_gemm_mfma<<<dim3(Mn / 128, Cn / 128), 256, 0, stream>>>(
        Yb, WtP, b_proj, out);
}

// Round 4
// 328.009 us; speedup vs baseline: 7.1656x; 1.3108x over previous
//
#include <hip/hip_runtime.h>
#include <hip/hip_bf16.h>

typedef short s16x8 __attribute__((ext_vector_type(8)));
typedef float f32x4 __attribute__((ext_vector_type(4)));

#define MFMA_BF16(A, B, C) __builtin_amdgcn_mfma_f32_16x16x32_bf16(A, B, C, 0, 0, 0)

constexpr int Bn = 4, Tn = 2048, Cn = 1024, Hn = 16, Dn = 64;
constexpr int Mn = Bn * Tn;      // 8192
constexpr int Nqkv = 3 * Cn;     // 3072

__device__ __forceinline__ ushort f2bfu(float f) {
    __hip_bfloat16 h = __float2bfloat16(f);
    return *reinterpret_cast<ushort*>(&h);
}

// async global->LDS, 16B per lane; LDS dest = wave-uniform base + lane*16.
__device__ __forceinline__ void gl_lds16(const void* g, void* l) {
    __builtin_amdgcn_global_load_lds(
        (const __attribute__((address_space(1))) void*)(uintptr_t)g,
        (__attribute__((address_space(3))) void*)(uint32_t)(uintptr_t)l,
        16, 0, 0);
}

// ---------------------------------------------------------------------------
// fp32 -> bf16 elementwise (x)
// ---------------------------------------------------------------------------
__global__ __launch_bounds__(256) void conv_bf16_kernel(
    const float* __restrict__ src, ushort* __restrict__ dst, int n4)
{
    int i = blockIdx.x * blockDim.x + threadIdx.x;
    int stride = gridDim.x * blockDim.x;
    for (; i < n4; i += stride) {
        float4 v = ((const float4*)src)[i];
        ushort4 o;
        o.x = f2bfu(v.x); o.y = f2bfu(v.y); o.z = f2bfu(v.z); o.w = f2bfu(v.w);
        ((ushort4*)dst)[i] = o;
    }
}

// ---------------------------------------------------------------------------
// W [K][N] fp32  ->  Wt [N][K] bf16   (64x64 tiles via LDS)
// ---------------------------------------------------------------------------
__global__ __launch_bounds__(256) void transpose_cvt_kernel(
    const float* __restrict__ W, ushort* __restrict__ Wt, int K, int N)
{
    __shared__ __align__(16) float Ls[64][68];
    const int t = threadIdx.x;
    const int n0 = blockIdx.x * 64, k0 = blockIdx.y * 64;
#pragma unroll
    for (int p = 0; p < 4; ++p) {
        int r = (t >> 4) + p * 16;
        int c = (t & 15) * 4;
        *(float4*)&Ls[r][c] = *(const float4*)&W[(size_t)(k0 + r) * N + n0 + c];
    }
    __syncthreads();
    const int n = t >> 2;
    const int ks = (t & 3) * 16;
    union { ushort s[16]; uint4 u[2]; } tmp;
#pragma unroll
    for (int j = 0; j < 16; ++j) tmp.s[j] = f2bfu(Ls[ks + j][n]);
    uint4* dp = (uint4*)&Wt[(size_t)(n0 + n) * K + k0 + ks];
    dp[0] = tmp.u[0];
    dp[1] = tmp.u[1];
}

// ---------------------------------------------------------------------------
// QKV GEMM, m97-style: global_load_lds(16B) staging into unpadded [128][64]
// LDS with XOR chunk swizzle (phys_chunk = logical_chunk ^ (row&7)).
// 128x128 tile, BK=64, 4 waves, 4x4 16x16x32 accs/wave.
// ---------------------------------------------------------------------------
__global__ __launch_bounds__(256) void qkv_gemm_mfma(
    const ushort* __restrict__ A, const ushort* __restrict__ Bt,
    const float* __restrict__ bias,
    ushort* __restrict__ Qo, ushort* __restrict__ Ko, ushort* __restrict__ Vo)
{
    __shared__ __align__(16) ushort As[128 * 64];
    __shared__ __align__(16) ushort Bs[128 * 64];
    const int tid = threadIdx.x;
    const int m0 = blockIdx.x * 128, n0 = blockIdx.y * 128;
    const int w = tid >> 6, lane = tid & 63, l15 = lane & 15, qd = lane >> 4;
    const int wm = (w >> 1) * 64, wn = (w & 1) * 64;
    const int lrow = lane >> 3;                    // 0..7 within 8-row group
    const int lchunk = (lane & 7) ^ (lrow & 7);    // logical k-chunk to fetch

    const ushort* gA = A + (size_t)(m0 + w * 32 + lrow) * Cn + lchunk * 8;
    const ushort* gB = Bt + (size_t)(n0 + w * 32 + lrow) * Cn + lchunk * 8;
    ushort* lA = &As[(w * 32) * 64];
    ushort* lB = &Bs[(w * 32) * 64];

    f32x4 acc[4][4] = {};

    for (int k0 = 0; k0 < Cn; k0 += 64) {
        __syncthreads();
#pragma unroll
        for (int t = 0; t < 4; ++t) {
            gl_lds16(gA + (size_t)t * 8 * Cn + k0, lA + t * 8 * 64);
            gl_lds16(gB + (size_t)t * 8 * Cn + k0, lB + t * 8 * 64);
        }
        __syncthreads();   // drains vmcnt: LDS tiles complete
#pragma unroll
        for (int ks = 0; ks < 2; ++ks) {
            const int xs = (((ks * 4 + qd) ^ (l15 & 7))) * 8;
            s16x8 af[4], bfr[4];
#pragma unroll
            for (int i = 0; i < 4; ++i) {
                af[i]  = *(const s16x8*)&As[(wm + i * 16 + l15) * 64 + xs];
                bfr[i] = *(const s16x8*)&Bs[(wn + i * 16 + l15) * 64 + xs];
            }
#pragma unroll
            for (int mt = 0; mt < 4; ++mt)
#pragma unroll
                for (int nt = 0; nt < 4; ++nt)
                    acc[mt][nt] = MFMA_BF16(af[mt], bfr[nt], acc[mt][nt]);
        }
    }

#pragma unroll
    for (int nt = 0; nt < 4; ++nt) {
        int n_g = n0 + wn + nt * 16 + l15;
        float bv = bias[n_g];
        int sel = n_g >> 10;
        int h = (n_g >> 6) & 15;
        int d = n_g & 63;
        ushort* O = (sel == 0) ? Qo : ((sel == 1) ? Ko : Vo);
#pragma unroll
        for (int mt = 0; mt < 4; ++mt) {
#pragma unroll
            for (int r = 0; r < 4; ++r) {
                int m_g = m0 + wm + mt * 16 + qd * 4 + r;
                int b = m_g >> 11, t = m_g & 2047;
                O[(((size_t)(b * Hn + h) * Tn + t) << 6) + d] =
                    f2bfu(acc[mt][nt][r] + bv);
            }
        }
    }
}

// ---------------------------------------------------------------------------
// Transposed MFMA flash attention: S^T = K·Q^T so q sits on the C-layout
// column axis. Per wave: 16 q-rows (cols) x 64 keys. Softmax state = one
// scalar per lane (replicated across qd groups via xor16/32 shuffles).
// P^T regs are key-consecutive -> ds_write_b64; PV = V^T·P^T with both
// fragments as ds_read_b128. O^T accumulates in C layout.
// ---------------------------------------------------------------------------
__global__ __launch_bounds__(256) void attn_mfma(
    const ushort* __restrict__ Q, const ushort* __restrict__ K,
    const ushort* __restrict__ V, ushort* __restrict__ Y)
{
    __shared__ __align__(16) ushort Qs[64][72];  // Q tile; wave rows reused for P^T
    __shared__ __align__(16) ushort Ks[64][72];  // [key][d]
    __shared__ __align__(16) ushort Vt[64][72];  // [d][key]

    const int tid = threadIdx.x;
    const int qt = blockIdx.x, bh = blockIdx.y;
    const int w = tid >> 6, lane = tid & 63, l15 = lane & 15, qd = lane >> 4;
    const size_t base = (size_t)bh * Tn * Dn;
    const int srow = tid >> 2;          // 0..63
    const int sseg = (tid & 3) * 16;    // 0,16,32,48

    // stage Q tile
    {
        const uint4* gq = (const uint4*)(Q + base + (size_t)(qt * 64 + srow) * Dn + sseg);
        uint4 q0 = gq[0], q1 = gq[1];
        *(uint4*)&Qs[srow][sseg + 0] = q0;
        *(uint4*)&Qs[srow][sseg + 8] = q1;
    }
    __syncthreads();
    s16x8 qf[2];   // B-operand fragment: b[q=l15][d=qd*8+j]
    qf[0] = *(const s16x8*)&Qs[w * 16 + l15][qd * 8];
    qf[1] = *(const s16x8*)&Qs[w * 16 + l15][32 + qd * 8];

    float m_run = -1e30f, l_run = 0.f;
    f32x4 o[4] = {};   // O^T[d=dt*16+qd*4+r][q=l15]

    const int vk = (tid & 15) * 4, vd = (tid >> 4) * 4;
    const int q_l = w * 16 + l15;

    for (int kt = 0; kt <= qt; ++kt) {
        __syncthreads();   // prev-iter Ks/Vt reads done
        {
            const uint4* gk = (const uint4*)(K + base + (size_t)(kt * 64 + srow) * Dn + sseg);
            uint4 k0 = gk[0], k1 = gk[1];
            *(uint4*)&Ks[srow][sseg + 0] = k0;
            *(uint4*)&Ks[srow][sseg + 8] = k1;
            // V 4x4 in-register transpose -> Vt[d][key], packed b64 writes
            const ushort* gv = V + base + (size_t)(kt * 64 + vk) * Dn + vd;
            ushort4 v0 = *(const ushort4*)(gv);
            ushort4 v1 = *(const ushort4*)(gv + Dn);
            ushort4 v2 = *(const ushort4*)(gv + 2 * Dn);
            ushort4 v3 = *(const ushort4*)(gv + 3 * Dn);
            ushort4 t0, t1, t2, t3;
            t0.x = v0.x; t0.y = v1.x; t0.z = v2.x; t0.w = v3.x;
            t1.x = v0.y; t1.y = v1.y; t1.z = v2.y; t1.w = v3.y;
            t2.x = v0.z; t2.y = v1.z; t2.z = v2.z; t2.w = v3.z;
            t3.x = v0.w; t3.y = v1.w; t3.z = v2.w; t3.w = v3.w;
            *(ushort4*)&Vt[vd + 0][vk] = t0;
            *(ushort4*)&Vt[vd + 1][vk] = t1;
            *(ushort4*)&Vt[vd + 2][vk] = t2;
            *(ushort4*)&Vt[vd + 3][vk] = t3;
        }
        __syncthreads();

        // S^T = K·Q^T : lane(qd,l15) reg(nt,r) = S^T[key=nt*16+qd*4+r][q=l15]
        f32x4 s[4] = {};
#pragma unroll
        for (int ks = 0; ks < 2; ++ks) {
#pragma unroll
            for (int nt = 0; nt < 4; ++nt) {
                s16x8 kf = *(const s16x8*)&Ks[nt * 16 + l15][ks * 32 + qd * 8];
                s[nt] = MFMA_BF16(kf, qf[ks], s[nt]);
            }
        }
#pragma unroll
        for (int nt = 0; nt < 4; ++nt)
#pragma unroll
            for (int r = 0; r < 4; ++r) s[nt][r] *= 0.125f;

        if (kt == qt) {
#pragma unroll
            for (int nt = 0; nt < 4; ++nt)
#pragma unroll
                for (int r = 0; r < 4; ++r)
                    if (nt * 16 + qd * 4 + r > q_l) s[nt][r] = -1e30f;
        }

        // online softmax over keys: 15 in-lane + 2 shuffles
        float mx = s[0][0];
#pragma unroll
        for (int nt = 0; nt < 4; ++nt)
#pragma unroll
            for (int r = 0; r < 4; ++r) mx = fmaxf(mx, s[nt][r]);
        mx = fmaxf(mx, __shfl_xor(mx, 16));
        mx = fmaxf(mx, __shfl_xor(mx, 32));
        float m_new = fmaxf(m_run, mx);
        float alpha = __expf(m_run - m_new);
        float ls = 0.f;
#pragma unroll
        for (int nt = 0; nt < 4; ++nt)
#pragma unroll
            for (int r = 0; r < 4; ++r) {
                float p = __expf(s[nt][r] - m_new);
                s[nt][r] = p;
                ls += p;
            }
        ls += __shfl_xor(ls, 16);
        ls += __shfl_xor(ls, 32);
        l_run = l_run * alpha + ls;
        m_run = m_new;
#pragma unroll
        for (int dt = 0; dt < 4; ++dt)
#pragma unroll
            for (int r = 0; r < 4; ++r) o[dt][r] *= alpha;

        // P^T -> wave-private LDS rows (key-consecutive regs -> b64 packs)
#pragma unroll
        for (int nt = 0; nt < 4; ++nt) {
            ushort4 pk;
            pk.x = f2bfu(s[nt][0]); pk.y = f2bfu(s[nt][1]);
            pk.z = f2bfu(s[nt][2]); pk.w = f2bfu(s[nt][3]);
            *(ushort4*)&Qs[w * 16 + l15][nt * 16 + qd * 4] = pk;
        }

        // O^T += V^T · P^T  (A-frag from Vt, B-frag from P^T row, both b128)
#pragma unroll
        for (int ks = 0; ks < 2; ++ks) {
            s16x8 pb = *(const s16x8*)&Qs[w * 16 + l15][ks * 32 + qd * 8];
#pragma unroll
            for (int dt = 0; dt < 4; ++dt) {
                s16x8 vf = *(const s16x8*)&Vt[dt * 16 + l15][ks * 32 + qd * 8];
                o[dt] = MFMA_BF16(vf, pb, o[dt]);
            }
        }
    }

    // epilogue: O^T[d][q=l15] -> Y[b, t=q_global, h*64+d], b64 packed stores
    const int b = bh >> 4, h = bh & 15;
    const float inv = 1.f / l_run;
    const int t_g = qt * 64 + w * 16 + l15;
    ushort* yp = Y + ((size_t)(b * Tn + t_g)) * Cn + h * Dn + qd * 4;
#pragma unroll
    for (int dt = 0; dt < 4; ++dt) {
        ushort4 pk;
        pk.x = f2bfu(o[dt][0] * inv);
        pk.y = f2bfu(o[dt][1] * inv);
        pk.z = f2bfu(o[dt][2] * inv);
        pk.w = f2bfu(o[dt][3] * inv);
        *(ushort4*)(yp + dt * 16) = pk;
    }
}

// ---------------------------------------------------------------------------
// Proj GEMM: Y [8192][1024] bf16, Wt [1024][1024] bf16 -> out fp32
// Same m97-style staging as qkv_gemm_mfma.
// ---------------------------------------------------------------------------
__global__ __launch_bounds__(256) void proj_gemm_mfma(
    const ushort* __restrict__ A, const ushort* __restrict__ Bt,
    const float* __restrict__ bias, float* __restrict__ out)
{
    __shared__ __align__(16) ushort As[128 * 64];
    __shared__ __align__(16) ushort Bs[128 * 64];
    const int tid = threadIdx.x;
    const int m0 = blockIdx.x * 128, n0 = blockIdx.y * 128;
    const int w = tid >> 6, lane = tid & 63, l15 = lane & 15, qd = lane >> 4;
    const int wm = (w >> 1) * 64, wn = (w & 1) * 64;
    const int lrow = lane >> 3;
    const int lchunk = (lane & 7) ^ (lrow & 7);

    const ushort* gA = A + (size_t)(m0 + w * 32 + lrow) * Cn + lchunk * 8;
    const ushort* gB = Bt + (size_t)(n0 + w * 32 + lrow) * Cn + lchunk * 8;
    ushort* lA = &As[(w * 32) * 64];
    ushort* lB = &Bs[(w * 32) * 64];

    f32x4 acc[4][4] = {};

    for (int k0 = 0; k0 < Cn; k0 += 64) {
        __syncthreads();
#pragma unroll
        for (int t = 0; t < 4; ++t) {
            gl_lds16(gA + (size_t)t * 8 * Cn + k0, lA + t * 8 * 64);
            gl_lds16(gB + (size_t)t * 8 * Cn + k0, lB + t * 8 * 64);
        }
        __syncthreads();
#pragma unroll
        for (int ks = 0; ks < 2; ++ks) {
            const int xs = (((ks * 4 + qd) ^ (l15 & 7))) * 8;
            s16x8 af[4], bfr[4];
#pragma unroll
            for (int i = 0; i < 4; ++i) {
                af[i]  = *(const s16x8*)&As[(wm + i * 16 + l15) * 64 + xs];
                bfr[i] = *(const s16x8*)&Bs[(wn + i * 16 + l15) * 64 + xs];
            }
#pragma unroll
            for (int mt = 0; mt < 4; ++mt)
#pragma unroll
                for (int nt = 0; nt < 4; ++nt)
                    acc[mt][nt] = MFMA_BF16(af[mt], bfr[nt], acc[mt][nt]);
        }
    }

#pragma unroll
    for (int nt = 0; nt < 4; ++nt) {
        int n_g = n0 + wn + nt * 16 + l15;
        float bv = bias[n_g];
#pragma unroll
        for (int mt = 0; mt < 4; ++mt) {
#pragma unroll
            for (int r = 0; r < 4; ++r) {
                int m_g = m0 + wm + mt * 16 + qd * 4 + r;
                out[(size_t)m_g * Cn + n_g] = acc[mt][nt][r] + bv;
            }
        }
    }
}

// ---------------------------------------------------------------------------
extern "C" void kernel_launch(void* const* d_in, const int* in_sizes, int n_in,
                              void* d_out, int out_size, void* d_ws, size_t ws_size,
                              hipStream_t stream) {
    const float* x      = (const float*)d_in[0];
    const float* W_attn = (const float*)d_in[1];
    const float* b_attn = (const float*)d_in[2];
    const float* W_proj = (const float*)d_in[3];
    const float* b_proj = (const float*)d_in[4];
    float* out = (float*)d_out;

    // ws: Q, K, V [B,H,T,D] bf16, Y [B,T,C] bf16
    constexpr size_t PER = (size_t)Mn * Cn;  // 8388608 elems
    ushort* Qb = (ushort*)d_ws;
    ushort* Kb = Qb + PER;
    ushort* Vb = Kb + PER;
    ushort* Yb = Vb + PER;

    // d_out doubles as pre-pass scratch (23 MB < 33.5 MB), dead before proj:
    ushort* WtA  = (ushort*)d_out;
    ushort* x_bf = WtA + (size_t)Nqkv * Cn;
    ushort* WtP  = Qb;   // reuses Q buffer (dead after attention)

    conv_bf16_kernel<<<1024, 256, 0, stream>>>(x, x_bf, (int)(PER / 4));
    transpose_cvt_kernel<<<dim3(Nqkv / 64, Cn / 64), 256, 0, stream>>>(
        W_attn, WtA, Cn, Nqkv);
    qkv_gemm_mfma<<<dim3(Mn / 128, Nqkv / 128), 256, 0, stream>>>(
        x_bf, WtA, b_attn, Qb, Kb, Vb);
    attn_mfma<<<dim3(Tn / 64, Bn * Hn), 256, 0, stream>>>(Qb, Kb, Vb, Yb);
    transpose_cvt_kernel<<<dim3(Cn / 64, Cn / 64), 256, 0, stream>>>(
        W_proj, WtP, Cn, Cn);
    proj_gemm_mfma<<<dim3(Mn / 128, Cn / 128), 256, 0, stream>>>(
        Yb, WtP, b_proj, out);
}